// Round 9
// baseline (92.241 us; speedup 1.0000x reference)
//
#include <hip/hip_runtime.h>

#define B_ 4096
#define D_ 512
#define STEPS_ 50

// All-VALU wave64 sum via DPP; lane63 holds total, readlane -> uniform.
#define DPP_ADD(x, ctrl) \
    ((x) + __int_as_float(__builtin_amdgcn_update_dpp( \
        0, __float_as_int(x), (ctrl), 0xf, 0xf, true)))

__device__ __forceinline__ float wave64_sum(float x) {
    x = DPP_ADD(x, 0x111);  // row_shr:1
    x = DPP_ADD(x, 0x112);  // row_shr:2
    x = DPP_ADD(x, 0x114);  // row_shr:4
    x = DPP_ADD(x, 0x118);  // row_shr:8
    x = DPP_ADD(x, 0x142);  // row_bcast:15
    x = DPP_ADD(x, 0x143);  // row_bcast:31
    return __int_as_float(__builtin_amdgcn_readlane(__float_as_int(x), 63));
}

// coef = (p - t)*p*(1-p), p = sigmoid(z); p(1-p) = e*p^2 with e = exp(-z).
// (2/B pre-folded into ws; z recovered via K = B/2.)
__device__ __forceinline__ float coef_from_z(float z, float t) {
    const float e = __expf(-z);
    const float q = __builtin_amdgcn_rcpf(1.0f + e);
    return (q - t) * (e * (q * q));
}

// ONE row per wave (4096 waves = 4 waves/SIMD), 8 elems/lane, all state in
// registers. Lesson from R4-R8: hand-rolled chain pipelines at 1-2
// waves/SIMD all plateau (~36 us) because EVERY latency is exposed at low
// TLP; R4's 4-wave TLP ran 67-75% busy with fatter math. This keeps R4's
// topology and applies the accumulated math lean-ups:
//  - update = An * M * rsq(V); V seeded +1e-30 once (0.999^50*1e-30 > 1e-31,
//    rsq never sees 0; matches reference 0/(0+eps)=0 for the g==0 row)
//  - An[t] = -(lr*0.1/(1-0.9^(t+1)))/sqrt(0.001/(1-0.999^(t+1))) in a
//    lane-indexed VGPR table, fetched per step via v_readlane (no s_loads)
//  - L1 grad term via single copysign (v_bfi)
//  - reduce+sigmoid chain at loop TOP: step 49's dot never computed; the
//    chain's ~200 cy is covered by the other 3 waves' element loops.
// __launch_bounds__(64,4): cap 128 VGPRs so 4 waves/SIMD are guaranteed.
__global__ __launch_bounds__(64, 4) void adam_rows_kernel(
    const float* __restrict__ s,
    const float* __restrict__ tgt,
    const float* __restrict__ W,
    const float* __restrict__ bias_p,
    float* __restrict__ out)
{
    const int lane = threadIdx.x;          // 0..63
    const int row  = blockIdx.x;

    // Lane-indexed An table (lanes >= 50 hold junk, never read).
    float vAn;
    {
        const float t1 = (float)(lane + 1);
        const float p1 = exp2f(t1 * -0.15200309344505f);    // 0.9^(t+1)
        const float p2 = exp2f(t1 * -0.00144345345258f);    // 0.999^(t+1)
        vAn = (-0.0316227766017f * __builtin_amdgcn_sqrtf(1.0f - p2)) *
              __builtin_amdgcn_rcpf(1.0f - p1);
    }

    const float c_mse = 0x1p-11f;          // 2/B, exact
    const float K     = 2048.0f;           // 1/c_mse
    const float c_l1  = 0x1p-21f;          // 1/(B*D)

    const float4* W4  = (const float4*)W;
    const float4* sr4 = (const float4*)(s + (size_t)row * D_);

    const float4 wa = W4[lane], wb = W4[lane + 64];
    float ws[8] = {wa.x * c_mse, wa.y * c_mse, wa.z * c_mse, wa.w * c_mse,
                   wb.x * c_mse, wb.y * c_mse, wb.z * c_mse, wb.w * c_mse};

    float dl[8], M[8], V[8];

    // zb = s.W + b (s loaded, consumed, not kept live through the loop).
    float zb;
    {
        const float4 sa = sr4[lane], sb = sr4[lane + 64];
        const float e[8] = {sa.x, sa.y, sa.z, sa.w, sb.x, sb.y, sb.z, sb.w};
        float za = 0.0f;
#pragma unroll
        for (int k = 0; k < 8; ++k) za = fmaf(e[k], ws[k], za);
        zb = fmaf(K, wave64_sum(za), bias_p[0]);
    }
    const float tg = tgt[row];

    float du;  // scaled dl.W partial feeding the next step's chain

    // ---- step 0 peeled: dl == 0 -> L1 term 0 ----
    {
        const float c0 = coef_from_z(zb, tg);
        const float An0 =
            __int_as_float(__builtin_amdgcn_readlane(__float_as_int(vAn), 0));
        float a = 0.0f;
#pragma unroll
        for (int k = 0; k < 8; ++k) {
            const float g = c0 * ws[k];
            M[k] = g;
            V[k] = fmaf(g, g, 1e-30f);
            dl[k] = (An0 * g) * __builtin_amdgcn_rsqf(V[k]);
            a = fmaf(dl[k], ws[k], a);
        }
        du = a;
    }

    // ---- steps 1..49: chain at loop top (step 49's du never consumed) ----
#pragma unroll 1
    for (int step = 1; step < STEPS_; ++step) {
        const float An =
            __int_as_float(__builtin_amdgcn_readlane(__float_as_int(vAn), step));
        const float c =
            coef_from_z(fmaf(K, wave64_sum(du), zb), tg);

        float a = 0.0f;
#pragma unroll
        for (int k = 0; k < 8; ++k) {
            const float g = fmaf(c, ws[k], __builtin_copysignf(c_l1, dl[k]));
            M[k] = fmaf(0.9f,   M[k], g);
            V[k] = fmaf(0.999f, V[k], g * g);
            dl[k] = fmaf(An * M[k], __builtin_amdgcn_rsqf(V[k]), dl[k]);
            a = fmaf(dl[k], ws[k], a);
        }
        du = a;
    }

    // Epilogue: re-load s and write x = s + dl.
    {
        const float4 sa = sr4[lane], sb = sr4[lane + 64];
        float4 oa = {sa.x + dl[0], sa.y + dl[1], sa.z + dl[2], sa.w + dl[3]};
        float4 ob = {sb.x + dl[4], sb.y + dl[5], sb.z + dl[6], sb.w + dl[7]};
        float4* orow = (float4*)(out + (size_t)row * D_);
        orow[lane]      = oa;
        orow[lane + 64] = ob;
    }
}

extern "C" void kernel_launch(void* const* d_in, const int* in_sizes, int n_in,
                              void* d_out, int out_size, void* d_ws, size_t ws_size,
                              hipStream_t stream) {
    const float* s    = (const float*)d_in[0];  // [4096, 512]
    const float* tgt  = (const float*)d_in[1];  // [4096, 1]
    const float* W    = (const float*)d_in[2];  // [1, 512]
    const float* bias = (const float*)d_in[3];  // [1]
    float* out = (float*)d_out;                 // [4096, 512]

    adam_rows_kernel<<<dim3(B_), dim3(64), 0, stream>>>(s, tgt, W, bias, out);
}

// Round 10
// 91.954 us; speedup vs baseline: 1.0031x; 1.0031x over previous
//
#include <hip/hip_runtime.h>

#define B_ 4096
#define D_ 512
#define STEPS_ 50

// All-VALU wave64 sum via DPP; lane63 holds total, readlane -> uniform.
#define DPP_ADD(x, ctrl) \
    ((x) + __int_as_float(__builtin_amdgcn_update_dpp( \
        0, __float_as_int(x), (ctrl), 0xf, 0xf, true)))

__device__ __forceinline__ float wave64_sum(float x) {
    x = DPP_ADD(x, 0x111);  // row_shr:1
    x = DPP_ADD(x, 0x112);  // row_shr:2
    x = DPP_ADD(x, 0x114);  // row_shr:4
    x = DPP_ADD(x, 0x118);  // row_shr:8
    x = DPP_ADD(x, 0x142);  // row_bcast:15
    x = DPP_ADD(x, 0x143);  // row_bcast:31
    return __int_as_float(__builtin_amdgcn_readlane(__float_as_int(x), 63));
}

// coef = (p - t)*p*(1-p), p = sigmoid(z); p(1-p) = e*p^2 with e = exp(-z).
__device__ __forceinline__ float coef_from_z(float z, float t) {
    const float e = __expf(-z);
    const float q = __builtin_amdgcn_rcpf(1.0f + e);
    return (q - t) * (e * (q * q));
}

// R9 structure (1 row/wave, 4 waves/SIMD, lean math) + PHASE STAGGER.
// Evidence R4-R9: idle/step/SIMD ~700-900cy regardless of chain count,
// rotation, or TLP -> co-resident waves run identical code and phase-lock,
// so every wave's serial reduce+sigmoid line is exposed simultaneously.
// Fix: one-time per-block s_sleep stagger (~450cy per phase step) so the 4
// waves/SIMD run ~1/4-step out of phase; each wave's chain is then covered
// by the other waves' element loops. Phase comes from a multi-scale hash of
// blockIdx because the block->SIMD mapping is undefined.
__global__ __launch_bounds__(64, 4) void adam_rows_kernel(
    const float* __restrict__ s,
    const float* __restrict__ tgt,
    const float* __restrict__ W,
    const float* __restrict__ bias_p,
    float* __restrict__ out)
{
    const int lane = threadIdx.x;          // 0..63
    const int row  = blockIdx.x;

    // Lane-indexed An table (lanes >= 50 hold junk, never read).
    // An[t] = -(lr*0.1/(1-0.9^(t+1)))/sqrt(0.001/(1-0.999^(t+1)))
    float vAn;
    {
        const float t1 = (float)(lane + 1);
        const float p1 = exp2f(t1 * -0.15200309344505f);    // 0.9^(t+1)
        const float p2 = exp2f(t1 * -0.00144345345258f);    // 0.999^(t+1)
        vAn = (-0.0316227766017f * __builtin_amdgcn_sqrtf(1.0f - p2)) *
              __builtin_amdgcn_rcpf(1.0f - p1);
    }

    const float c_mse = 0x1p-11f;          // 2/B, exact
    const float K     = 2048.0f;           // 1/c_mse
    const float c_l1  = 0x1p-21f;          // 1/(B*D)

    const float4* W4  = (const float4*)W;
    const float4* sr4 = (const float4*)(s + (size_t)row * D_);

    const float4 wa = W4[lane], wb = W4[lane + 64];
    float ws[8] = {wa.x * c_mse, wa.y * c_mse, wa.z * c_mse, wa.w * c_mse,
                   wb.x * c_mse, wb.y * c_mse, wb.z * c_mse, wb.w * c_mse};

    float dl[8], M[8], V[8];

    // zb = s.W + b (s loaded, consumed, not kept live through the loop).
    float zb;
    {
        const float4 sa = sr4[lane], sb = sr4[lane + 64];
        const float e[8] = {sa.x, sa.y, sa.z, sa.w, sb.x, sb.y, sb.z, sb.w};
        float za = 0.0f;
#pragma unroll
        for (int k = 0; k < 8; ++k) za = fmaf(e[k], ws[k], za);
        zb = fmaf(K, wave64_sum(za), bias_p[0]);
    }
    const float tg = tgt[row];

    // ---- PHASE STAGGER: desynchronize co-resident waves. s_sleep is off
    // the issue pipe; ~448cy per s_sleep(7). Hash covers strides 4..1024 so
    // any plausible block->SIMD mapping yields mixed phases per SIMD.
    {
        const unsigned b = (unsigned)blockIdx.x;
        const int phase =
            (int)((b ^ (b >> 2) ^ (b >> 4) ^ (b >> 6) ^ (b >> 8) ^ (b >> 10)) & 3u);
#pragma unroll 1
        for (int i = 0; i < phase; ++i) __builtin_amdgcn_s_sleep(7);
    }

    float du;  // scaled dl.W partial feeding the next step's chain

    // ---- step 0 peeled: dl == 0 -> L1 term 0; V seeded +1e-30 ----
    {
        const float c0 = coef_from_z(zb, tg);
        const float An0 =
            __int_as_float(__builtin_amdgcn_readlane(__float_as_int(vAn), 0));
        float a = 0.0f;
#pragma unroll
        for (int k = 0; k < 8; ++k) {
            const float g = c0 * ws[k];
            M[k] = g;
            V[k] = fmaf(g, g, 1e-30f);
            dl[k] = (An0 * g) * __builtin_amdgcn_rsqf(V[k]);
            a = fmaf(dl[k], ws[k], a);
        }
        du = a;
    }

    // ---- steps 1..49: chain at loop top ----
#pragma unroll 1
    for (int step = 1; step < STEPS_; ++step) {
        const float An =
            __int_as_float(__builtin_amdgcn_readlane(__float_as_int(vAn), step));
        const float c = coef_from_z(fmaf(K, wave64_sum(du), zb), tg);

        float a = 0.0f;
#pragma unroll
        for (int k = 0; k < 8; ++k) {
            const float g = fmaf(c, ws[k], __builtin_copysignf(c_l1, dl[k]));
            M[k] = fmaf(0.9f,   M[k], g);
            V[k] = fmaf(0.999f, V[k], g * g);
            dl[k] = fmaf(An * M[k], __builtin_amdgcn_rsqf(V[k]), dl[k]);
            a = fmaf(dl[k], ws[k], a);
        }
        du = a;
    }

    // Epilogue: re-load s and write x = s + dl.
    {
        const float4 sa = sr4[lane], sb = sr4[lane + 64];
        float4 oa = {sa.x + dl[0], sa.y + dl[1], sa.z + dl[2], sa.w + dl[3]};
        float4 ob = {sb.x + dl[4], sb.y + dl[5], sb.z + dl[6], sb.w + dl[7]};
        float4* orow = (float4*)(out + (size_t)row * D_);
        orow[lane]      = oa;
        orow[lane + 64] = ob;
    }
}

extern "C" void kernel_launch(void* const* d_in, const int* in_sizes, int n_in,
                              void* d_out, int out_size, void* d_ws, size_t ws_size,
                              hipStream_t stream) {
    const float* s    = (const float*)d_in[0];  // [4096, 512]
    const float* tgt  = (const float*)d_in[1];  // [4096, 1]
    const float* W    = (const float*)d_in[2];  // [1, 512]
    const float* bias = (const float*)d_in[3];  // [1]
    float* out = (float*)d_out;                 // [4096, 512]

    adam_rows_kernel<<<dim3(B_), dim3(64), 0, stream>>>(s, tgt, W, bias, out);
}